// Round 5
// baseline (420.393 us; speedup 1.0000x reference)
//
#include <hip/hip_runtime.h>
#include <hip/hip_bf16.h>
#include <stdint.h>

#define B_N 4
#define S_N 2048
#define DIM_N 1024
#define H_N 16
#define DH_N 64
#define M_ROWS (B_N * S_N)   /* 8192 */
#define BH_N (B_N * H_N)     /* 64 */
#define C1 0.18033688011112042f   /* 0.125 * log2(e) */

typedef unsigned short u16;
typedef __attribute__((ext_vector_type(8))) short short8;
typedef __attribute__((ext_vector_type(4))) float f32x4;
typedef __attribute__((ext_vector_type(16))) float f32x16;

typedef __attribute__((address_space(1))) const void gvoid_t;
typedef __attribute__((address_space(3))) void lvoid_t;

__device__ __forceinline__ u16 f2bf(float f) {
  union { float f; uint32_t u; } c; c.f = f;
  uint32_t u = c.u;
  return (u16)((u + 0x7FFFu + ((u >> 16) & 1u)) >> 16);
}

__device__ __forceinline__ uint32_t pk_bf16(float lo, float hi) {
  uint32_t r;
  asm("v_cvt_pk_bf16_f32 %0, %1, %2" : "=v"(r) : "v"(lo), "v"(hi));
  return r;
}

// ---------------- fp32 -> bf16 conversion (vectorized) ----------------
__global__ void cvt_kernel(const float* __restrict__ src, u16* __restrict__ dst, int n4) {
  int i = blockIdx.x * blockDim.x + threadIdx.x;
  if (i >= n4) return;
  float4 v = reinterpret_cast<const float4*>(src)[i];
  ushort4 o;
  o.x = f2bf(v.x); o.y = f2bf(v.y); o.z = f2bf(v.z); o.w = f2bf(v.w);
  reinterpret_cast<ushort4*>(dst)[i] = o;
}

// ---------------- mask -> packed bits (1 bit per bool, 32 keys/word) ------
__global__ void pack_mask(const uint8_t* __restrict__ m, uint32_t* __restrict__ bits, int nwords) {
  int i = blockIdx.x * blockDim.x + threadIdx.x;
  if (i >= nwords) return;
  const uint32_t* p = reinterpret_cast<const uint32_t*>(m) + (size_t)i * 8;
  uint32_t out = 0;
#pragma unroll
  for (int w = 0; w < 8; ++w) {
    uint32_t v = p[w];
    if (v & 0x000000FFu) out |= 1u << (w * 4 + 0);
    if (v & 0x0000FF00u) out |= 1u << (w * 4 + 1);
    if (v & 0x00FF0000u) out |= 1u << (w * 4 + 2);
    if (v & 0xFF000000u) out |= 1u << (w * 4 + 3);
  }
  bits[i] = out;
}

// ---------------- bf16 GEMM, C[m][n] = (sum_k A[m][k]*Bw[n][k] + bias[n])*scale
// MODE 0: bf16 out, permuted [b,h,s,d]   (Q with scale=C1, K with scale=1)
// MODE 1: bf16 out, transposed [b,h,d,s'] with within-16 key permutation
//         s' = s^12 for (s&15) in [4,12)  -- pairs with attn's lane-local P pack
// MODE 2: fp32 out, row-major [m][n]     (final output projection)
template<int MODE>
__global__ __launch_bounds__(256)
void gemm_bt(const u16* __restrict__ A, const u16* __restrict__ Bw,
             const float* __restrict__ bias, void* __restrict__ outp, float scale)
{
  __shared__ __align__(16) u16 As[128 * 32];
  __shared__ __align__(16) u16 Bs[128 * 32];
  const int m0 = blockIdx.x * 128, n0 = blockIdx.y * 128;
  const int t = threadIdx.x, w = t >> 6;
  const int l = t & 63, lr = l & 15, lg = l >> 4;
  const int wr = (w >> 1) * 64, wc = (w & 1) * 64;
  const int srow = t >> 2;
  const int skoff = (t & 3) * 8;

  f32x4 acc[4][4] = {};

  for (int k0 = 0; k0 < DIM_N; k0 += 32) {
    __syncthreads();
#pragma unroll
    for (int c = 0; c < 2; ++c) {
      const u16* ga = A  + (size_t)(m0 + c * 64 + srow) * DIM_N + k0 + skoff;
      const u16* gb = Bw + (size_t)(n0 + c * 64 + srow) * DIM_N + k0 + skoff;
      u16* la = &As[(c * 64 + 16 * w) * 32];
      u16* lb = &Bs[(c * 64 + 16 * w) * 32];
      __builtin_amdgcn_global_load_lds((gvoid_t*)ga, (lvoid_t*)la, 16, 0, 0);
      __builtin_amdgcn_global_load_lds((gvoid_t*)gb, (lvoid_t*)lb, 16, 0, 0);
    }
    __syncthreads();

    short8 af[4], bfr[4];
#pragma unroll
    for (int mf = 0; mf < 4; ++mf)
      af[mf] = *reinterpret_cast<const short8*>(&As[(wr + mf * 16 + lr) * 32 + lg * 8]);
#pragma unroll
    for (int nf = 0; nf < 4; ++nf)
      bfr[nf] = *reinterpret_cast<const short8*>(&Bs[(wc + nf * 16 + lr) * 32 + lg * 8]);
#pragma unroll
    for (int mf = 0; mf < 4; ++mf)
#pragma unroll
      for (int nf = 0; nf < 4; ++nf)
        acc[mf][nf] = __builtin_amdgcn_mfma_f32_16x16x32_bf16(af[mf], bfr[nf], acc[mf][nf], 0, 0, 0);
  }

  float bv[4];
#pragma unroll
  for (int nf = 0; nf < 4; ++nf) bv[nf] = bias[n0 + wc + nf * 16 + lr];

#pragma unroll
  for (int mf = 0; mf < 4; ++mf)
#pragma unroll
    for (int nf = 0; nf < 4; ++nf)
#pragma unroll
      for (int r = 0; r < 4; ++r) {
        int grow = m0 + wr + mf * 16 + lg * 4 + r;
        int gcol = n0 + wc + nf * 16 + lr;
        float v = (acc[mf][nf][r] + bv[nf]) * scale;
        if (MODE == 2) {
          ((float*)outp)[(size_t)grow * DIM_N + gcol] = v;
        } else {
          int b = grow >> 11, s = grow & 2047;
          int h = gcol >> 6, d = gcol & 63;
          size_t idx;
          if (MODE == 0) {
            idx = ((size_t)(b * H_N + h) * S_N + s) * DH_N + d;
          } else {
            int sp = ((((s & 15) + 4) & 8) ? (s ^ 12) : s);  // within-16 key perm
            idx = ((size_t)(b * H_N + h) * DH_N + d) * S_N + sp;
          }
          ((u16*)outp)[idx] = f2bf(v);
        }
      }
}

// ---------------- flash attention, swapped-operand 32x32, T15 pipeline ----
// grid: (S/128, B*H). 4 independent waves/block, 32 q-rows each.
// No LDS, no barriers, ZERO shuffles in the steady-state loop:
//  - P-pack is lane-local thanks to the V^T key permutation (MODE 1)
//  - l_run cross-half sum deferred to finalize
//  - cross-half max only inside the rare rescale branch
// Schedule: S(i+1) QK MFMAs issue BEFORE F(i) softmax+PV -> chains overlap.
#define AT_WAVES 4
#define NCHUNK (S_N / 32)

__global__ __launch_bounds__(256)
void attn_kernel(const u16* __restrict__ Qh, const u16* __restrict__ Kh,
                 const u16* __restrict__ Vt, const uint32_t* __restrict__ mbits,
                 u16* __restrict__ AO)
{
  const int w = threadIdx.x >> 6, l = threadIdx.x & 63;
  const int l31 = l & 31, hl = l >> 5;
  const int bh = blockIdx.y, b = bh >> 4, h = bh & 15;
  const int q = blockIdx.x * (AT_WAVES * 32) + w * 32 + l31;

  const u16* Qp = Qh + (size_t)bh * S_N * DH_N;
  const u16* Kp = Kh + (size_t)bh * S_N * DH_N;
  const u16* Vp = Vt + (size_t)bh * DH_N * S_N;
  const uint32_t* mrow = mbits + ((size_t)b * S_N + q) * NCHUNK;

  // Q as B-operand (col = l&31 = q, k-dim d = 16u + 8*hl + j), pre-scaled by C1
  short8 qf[4];
#pragma unroll
  for (int u = 0; u < 4; ++u)
    qf[u] = *reinterpret_cast<const short8*>(Qp + (size_t)q * DH_N + u * 16 + hl * 8);

  f32x16 oacc[2] = {};
  float m_run = -1e30f, l_run = 0.f;

  auto loadK = [&](int kc, short8 kf[4]) {
    const u16* kbase = Kp + (size_t)(kc * 32 + l31) * DH_N + hl * 8;
    kf[0] = *reinterpret_cast<const short8*>(kbase);
    kf[1] = *reinterpret_cast<const short8*>(kbase + 16);
    kf[2] = *reinterpret_cast<const short8*>(kbase + 32);
    kf[3] = *reinterpret_cast<const short8*>(kbase + 48);
  };

  // S-phase: QK^T for one chunk into sacc (exp2-domain scores; Q pre-scaled)
  auto sphase = [&](f32x16& sacc, const short8 kf[4]) {
    f32x16 z = {};
    __builtin_amdgcn_s_setprio(1);
    z = __builtin_amdgcn_mfma_f32_32x32x16_bf16(kf[0], qf[0], z, 0, 0, 0);
    z = __builtin_amdgcn_mfma_f32_32x32x16_bf16(kf[1], qf[1], z, 0, 0, 0);
    z = __builtin_amdgcn_mfma_f32_32x32x16_bf16(kf[2], qf[2], z, 0, 0, 0);
    z = __builtin_amdgcn_mfma_f32_32x32x16_bf16(kf[3], qf[3], z, 0, 0, 0);
    __builtin_amdgcn_s_setprio(0);
    sacc = z;
  };

  // F-phase: mask, defer-max softmax, lane-local pack, PV accumulate
  auto fphase = [&](f32x16& sacc, uint32_t mw, int kc) {
    // V loads issued first; consumed at PV after the softmax chain
    short8 vf[2][2];
#pragma unroll
    for (int ks = 0; ks < 2; ++ks)
#pragma unroll
      for (int nf = 0; nf < 2; ++nf)
        vf[ks][nf] = *reinterpret_cast<const short8*>(
            Vp + (size_t)(nf * 32 + l31) * S_N + kc * 32 + ks * 16 + hl * 8);

    if (mw) {
#pragma unroll
      for (int r = 0; r < 16; ++r)
        if ((mw >> ((r & 3) + 8 * (r >> 2) + 4 * hl)) & 1) sacc[r] = -1e30f;
    }

    // lane-local tree max (no cross-half shuffle on the hot path)
    float m8[8], m4[4];
#pragma unroll
    for (int r = 0; r < 8; ++r) m8[r] = fmaxf(sacc[2 * r], sacc[2 * r + 1]);
#pragma unroll
    for (int r = 0; r < 4; ++r) m4[r] = fmaxf(m8[2 * r], m8[2 * r + 1]);
    float mx = fmaxf(fmaxf(m4[0], m4[1]), fmaxf(m4[2], m4[3]));

    // defer-max: __all sees all 64 lanes, so any-half overflow triggers
    if (!__all(mx <= m_run + 8.0f)) {
      mx = fmaxf(mx, __shfl_xor(mx, 32));   // rare path only
      float mnew = fmaxf(m_run, mx);
      float al = __builtin_amdgcn_exp2f(m_run - mnew);
      l_run *= al;
#pragma unroll
      for (int r = 0; r < 16; ++r) { oacc[0][r] *= al; oacc[1][r] *= al; }
      m_run = mnew;
    }

    float p[16];
#pragma unroll
    for (int r = 0; r < 16; ++r) p[r] = __builtin_amdgcn_exp2f(sacc[r] - m_run);
    float a8[8], a4[4];
#pragma unroll
    for (int r = 0; r < 8; ++r) a8[r] = p[2 * r] + p[2 * r + 1];
#pragma unroll
    for (int r = 0; r < 4; ++r) a4[r] = a8[2 * r] + a8[2 * r + 1];
    l_run += (a4[0] + a4[1]) + (a4[2] + a4[3]);   // per-lane; cross-half at end

    // lane-local P pack (V^T key-permuted so B-frag element j == p[j])
    union { uint32_t u[4]; short8 s8; } pf0, pf1;
    pf0.u[0] = pk_bf16(p[0], p[1]);   pf0.u[1] = pk_bf16(p[2], p[3]);
    pf0.u[2] = pk_bf16(p[4], p[5]);   pf0.u[3] = pk_bf16(p[6], p[7]);
    pf1.u[0] = pk_bf16(p[8], p[9]);   pf1.u[1] = pk_bf16(p[10], p[11]);
    pf1.u[2] = pk_bf16(p[12], p[13]); pf1.u[3] = pk_bf16(p[14], p[15]);

    __builtin_amdgcn_s_setprio(1);
    oacc[0] = __builtin_amdgcn_mfma_f32_32x32x16_bf16(vf[0][0], pf0.s8, oacc[0], 0, 0, 0);
    oacc[1] = __builtin_amdgcn_mfma_f32_32x32x16_bf16(vf[0][1], pf0.s8, oacc[1], 0, 0, 0);
    oacc[0] = __builtin_amdgcn_mfma_f32_32x32x16_bf16(vf[1][0], pf1.s8, oacc[0], 0, 0, 0);
    oacc[1] = __builtin_amdgcn_mfma_f32_32x32x16_bf16(vf[1][1], pf1.s8, oacc[1], 0, 0, 0);
    __builtin_amdgcn_s_setprio(0);
  };

  // ---- pipeline: prologue S(0); loop { S(i+1) ; F(i) }; tail F(63) ----
  short8 kA[4], kB[4];
  f32x16 saccA, saccB;
  uint32_t mwA, mwB;

  loadK(0, kA);
  mwA = mrow[0];
  sphase(saccA, kA);          // S(0) — waits K0 once
  loadK(1, kB);

  for (int it = 0; it < 31; ++it) {
    const int i = 2 * it;
    // iterA: S(i+1) from kB; prefetch K(i+2)->kA; F(i) on saccA
    sphase(saccB, kB);
    loadK(i + 2, kA);
    mwB = mrow[i + 1];
    fphase(saccA, mwA, i);
    // iterB: S(i+2) from kA; prefetch K(i+3)->kB; F(i+1) on saccB
    sphase(saccA, kA);
    loadK(i + 3, kB);
    mwA = mrow[i + 2];
    fphase(saccB, mwB, i + 1);
  }
  // exit: saccA = S(62), mwA = mrow[62], kB = K(63)
  sphase(saccB, kB);          // S(63)
  uint32_t mw63 = mrow[63];
  fphase(saccA, mwA, 62);
  fphase(saccB, mw63, 63);

  // --- finalize: one cross-half sum, then O^T[d][q]/l -> AO[b,q,h*64+d] ---
  float l_tot = l_run + __shfl_xor(l_run, 32);
  float inv_l = 1.0f / l_tot;
  u16* orow = AO + ((size_t)b * S_N + q) * DIM_N + h * DH_N;
#pragma unroll
  for (int nf = 0; nf < 2; ++nf)
#pragma unroll
    for (int g = 0; g < 4; ++g) {
      ushort4 v4;
      v4.x = f2bf(oacc[nf][g * 4 + 0] * inv_l);
      v4.y = f2bf(oacc[nf][g * 4 + 1] * inv_l);
      v4.z = f2bf(oacc[nf][g * 4 + 2] * inv_l);
      v4.w = f2bf(oacc[nf][g * 4 + 3] * inv_l);
      *reinterpret_cast<ushort4*>(orow + nf * 32 + g * 8 + hl * 4) = v4;
    }
}

// ---------------- launch ----------------
extern "C" void kernel_launch(void* const* d_in, const int* in_sizes, int n_in,
                              void* d_out, int out_size, void* d_ws, size_t ws_size,
                              hipStream_t stream)
{
  const float*   q_in = (const float*)d_in[0];
  const float*   k_in = (const float*)d_in[1];
  const float*   v_in = (const float*)d_in[2];
  const uint8_t* mask = (const uint8_t*)d_in[3];
  const float*   w_q  = (const float*)d_in[4];
  const float*   b_q  = (const float*)d_in[5];
  const float*   w_k  = (const float*)d_in[6];
  const float*   b_k  = (const float*)d_in[7];
  const float*   w_v  = (const float*)d_in[8];
  const float*   b_v  = (const float*)d_in[9];
  const float*   w_o  = (const float*)d_in[10];
  const float*   b_o  = (const float*)d_in[11];

  char* ws = (char*)d_ws;
  size_t off = 0;
  auto alloc = [&](size_t bytes) -> char* {
    char* p = ws + off;
    off += (bytes + 255) & ~(size_t)255;
    return p;
  };
  const size_t act_b = (size_t)M_ROWS * DIM_N * 2;
  const size_t w_b   = (size_t)DIM_N * DIM_N * 2;
  const int    nmw   = B_N * S_N * (S_N / 32);       // 524288 mask words
  u16* qb  = (u16*)alloc(act_b);
  u16* kb  = (u16*)alloc(act_b);
  u16* vb  = (u16*)alloc(act_b);
  u16* wqb = (u16*)alloc(w_b);
  u16* wkb = (u16*)alloc(w_b);
  u16* wvb = (u16*)alloc(w_b);
  u16* wob = (u16*)alloc(w_b);
  u16* Qh  = (u16*)alloc(act_b);
  u16* Kh  = (u16*)alloc(act_b);
  u16* Vt  = (u16*)alloc(act_b);
  uint32_t* mbits = (uint32_t*)alloc((size_t)nmw * 4);
  u16* AO  = qb;   // qb dead after Q projection; reuse for merged attn out

  const int n4a = M_ROWS * DIM_N / 4;
  const int n4w = DIM_N * DIM_N / 4;
  cvt_kernel<<<n4a / 256, 256, 0, stream>>>(q_in, qb, n4a);
  cvt_kernel<<<n4a / 256, 256, 0, stream>>>(k_in, kb, n4a);
  cvt_kernel<<<n4a / 256, 256, 0, stream>>>(v_in, vb, n4a);
  cvt_kernel<<<n4w / 256, 256, 0, stream>>>(w_q, wqb, n4w);
  cvt_kernel<<<n4w / 256, 256, 0, stream>>>(w_k, wkb, n4w);
  cvt_kernel<<<n4w / 256, 256, 0, stream>>>(w_v, wvb, n4w);
  cvt_kernel<<<n4w / 256, 256, 0, stream>>>(w_o, wob, n4w);
  pack_mask<<<nmw / 256, 256, 0, stream>>>(mask, mbits, nmw);

  dim3 gg(M_ROWS / 128, DIM_N / 128);
  gemm_bt<0><<<gg, 256, 0, stream>>>(qb, wqb, b_q, Qh, C1);
  gemm_bt<0><<<gg, 256, 0, stream>>>(kb, wkb, b_k, Kh, 1.0f);
  gemm_bt<1><<<gg, 256, 0, stream>>>(vb, wvb, b_v, Vt, 1.0f);

  attn_kernel<<<dim3(S_N / (AT_WAVES * 32), BH_N), 256, 0, stream>>>(Qh, Kh, Vt, mbits, AO);

  gemm_bt<2><<<gg, 256, 0, stream>>>(AO, wob, b_o, (float*)d_out, 1.0f);
}

// Round 6
// 286.930 us; speedup vs baseline: 1.4651x; 1.4651x over previous
//
#include <hip/hip_runtime.h>
#include <hip/hip_bf16.h>
#include <stdint.h>

#define B_N 4
#define S_N 2048
#define DIM_N 1024
#define H_N 16
#define DH_N 64
#define M_ROWS (B_N * S_N)   /* 8192 */
#define BH_N (B_N * H_N)     /* 64 */
#define C1 0.18033688011112042f   /* 0.125 * log2(e) */

typedef unsigned short u16;
typedef __attribute__((ext_vector_type(8))) short short8;
typedef __attribute__((ext_vector_type(4))) float f32x4;
typedef __attribute__((ext_vector_type(16))) float f32x16;

typedef __attribute__((address_space(1))) const void gvoid_t;
typedef __attribute__((address_space(3))) void lvoid_t;

__device__ __forceinline__ u16 f2bf(float f) {
  union { float f; uint32_t u; } c; c.f = f;
  uint32_t u = c.u;
  return (u16)((u + 0x7FFFu + ((u >> 16) & 1u)) >> 16);
}

__device__ __forceinline__ uint32_t pk_bf16(float lo, float hi) {
  uint32_t r;
  asm("v_cvt_pk_bf16_f32 %0, %1, %2" : "=v"(r) : "v"(lo), "v"(hi));
  return r;
}

// ---------------- fp32 -> bf16 conversion (vectorized) ----------------
__global__ void cvt_kernel(const float* __restrict__ src, u16* __restrict__ dst, int n4) {
  int i = blockIdx.x * blockDim.x + threadIdx.x;
  if (i >= n4) return;
  float4 v = reinterpret_cast<const float4*>(src)[i];
  ushort4 o;
  o.x = f2bf(v.x); o.y = f2bf(v.y); o.z = f2bf(v.z); o.w = f2bf(v.w);
  reinterpret_cast<ushort4*>(dst)[i] = o;
}

// ---------------- mask -> packed bits (1 bit per bool, 32 keys/word) ------
__global__ void pack_mask(const uint8_t* __restrict__ m, uint32_t* __restrict__ bits, int nwords) {
  int i = blockIdx.x * blockDim.x + threadIdx.x;
  if (i >= nwords) return;
  const uint32_t* p = reinterpret_cast<const uint32_t*>(m) + (size_t)i * 8;
  uint32_t out = 0;
#pragma unroll
  for (int w = 0; w < 8; ++w) {
    uint32_t v = p[w];
    if (v & 0x000000FFu) out |= 1u << (w * 4 + 0);
    if (v & 0x0000FF00u) out |= 1u << (w * 4 + 1);
    if (v & 0x00FF0000u) out |= 1u << (w * 4 + 2);
    if (v & 0xFF000000u) out |= 1u << (w * 4 + 3);
  }
  bits[i] = out;
}

// ---------------- bf16 GEMM, C[m][n] = (sum_k A[m][k]*Bw[n][k] + bias[n])*scale
// MODE 0: bf16 out, permuted [b,h,s,d]   (Q with scale=C1, K with scale=1)
// MODE 1: bf16 out, transposed [b,h,d,s'] with within-16 key permutation
//         s' = s^12 for (s&15) in [4,12)  -- pairs with attn's lane-local P pack
// MODE 2: fp32 out, row-major [m][n]     (final output projection)
template<int MODE>
__global__ __launch_bounds__(256)
void gemm_bt(const u16* __restrict__ A, const u16* __restrict__ Bw,
             const float* __restrict__ bias, void* __restrict__ outp, float scale)
{
  __shared__ __align__(16) u16 As[128 * 32];
  __shared__ __align__(16) u16 Bs[128 * 32];
  const int m0 = blockIdx.x * 128, n0 = blockIdx.y * 128;
  const int t = threadIdx.x, w = t >> 6;
  const int l = t & 63, lr = l & 15, lg = l >> 4;
  const int wr = (w >> 1) * 64, wc = (w & 1) * 64;
  const int srow = t >> 2;
  const int skoff = (t & 3) * 8;

  f32x4 acc[4][4] = {};

  for (int k0 = 0; k0 < DIM_N; k0 += 32) {
    __syncthreads();
#pragma unroll
    for (int c = 0; c < 2; ++c) {
      const u16* ga = A  + (size_t)(m0 + c * 64 + srow) * DIM_N + k0 + skoff;
      const u16* gb = Bw + (size_t)(n0 + c * 64 + srow) * DIM_N + k0 + skoff;
      u16* la = &As[(c * 64 + 16 * w) * 32];
      u16* lb = &Bs[(c * 64 + 16 * w) * 32];
      __builtin_amdgcn_global_load_lds((gvoid_t*)ga, (lvoid_t*)la, 16, 0, 0);
      __builtin_amdgcn_global_load_lds((gvoid_t*)gb, (lvoid_t*)lb, 16, 0, 0);
    }
    __syncthreads();

    short8 af[4], bfr[4];
#pragma unroll
    for (int mf = 0; mf < 4; ++mf)
      af[mf] = *reinterpret_cast<const short8*>(&As[(wr + mf * 16 + lr) * 32 + lg * 8]);
#pragma unroll
    for (int nf = 0; nf < 4; ++nf)
      bfr[nf] = *reinterpret_cast<const short8*>(&Bs[(wc + nf * 16 + lr) * 32 + lg * 8]);
#pragma unroll
    for (int mf = 0; mf < 4; ++mf)
#pragma unroll
      for (int nf = 0; nf < 4; ++nf)
        acc[mf][nf] = __builtin_amdgcn_mfma_f32_16x16x32_bf16(af[mf], bfr[nf], acc[mf][nf], 0, 0, 0);
  }

  float bv[4];
#pragma unroll
  for (int nf = 0; nf < 4; ++nf) bv[nf] = bias[n0 + wc + nf * 16 + lr];

#pragma unroll
  for (int mf = 0; mf < 4; ++mf)
#pragma unroll
    for (int nf = 0; nf < 4; ++nf)
#pragma unroll
      for (int r = 0; r < 4; ++r) {
        int grow = m0 + wr + mf * 16 + lg * 4 + r;
        int gcol = n0 + wc + nf * 16 + lr;
        float v = (acc[mf][nf][r] + bv[nf]) * scale;
        if (MODE == 2) {
          ((float*)outp)[(size_t)grow * DIM_N + gcol] = v;
        } else {
          int b = grow >> 11, s = grow & 2047;
          int h = gcol >> 6, d = gcol & 63;
          size_t idx;
          if (MODE == 0) {
            idx = ((size_t)(b * H_N + h) * S_N + s) * DH_N + d;
          } else {
            int sp = ((((s & 15) + 4) & 8) ? (s ^ 12) : s);  // within-16 key perm
            idx = ((size_t)(b * H_N + h) * DH_N + d) * S_N + sp;
          }
          ((u16*)outp)[idx] = f2bf(v);
        }
      }
}

// ---------------- flash attention: LDS-staged KV + XCD-pinned bh ----------
// grid (16, 64) remapped so all 16 q-blocks of a bh share linear%8 -> one XCD
// (per-XCD KV = 8 bh x 512KB = 4MB = fits that XCD's L2).
// K,V staged per 64-key chunk into double-buffered LDS via global_load_lds
// (16B DMA, pre-swizzled global source: unit' = unit ^ (row&7); ds_reads apply
// the same XOR -> conflict-free). 2-phase: STAGE(next); compute(cur); barrier.
// Softmax: lane-local (V^T key-permutation), defer-max, exp2 domain.
#define AT_WAVES 4
#define KVB 64
#define NCH (S_N / KVB)   /* 32 */

__global__ __launch_bounds__(256)
void attn_kernel(const u16* __restrict__ Qh, const u16* __restrict__ Kh,
                 const u16* __restrict__ Vt, const uint32_t* __restrict__ mbits,
                 u16* __restrict__ AO)
{
  __shared__ __align__(16) u16 K_lds[2][KVB * DH_N];   // 8KB per buf
  __shared__ __align__(16) u16 V_lds[2][DH_N * KVB];   // 8KB per buf

  const int t = threadIdx.x;
  const int w = t >> 6, l = t & 63;
  const int l31 = l & 31, hl = l >> 5;
  const int kx = l31 & 7;

  // XCD remap (bijective): n = 64*xq + 8*j + i  ->  bh = 8i+j, xcd = i = bh>>3
  const int n = blockIdx.x + 16 * blockIdx.y;
  const int bh = (n & 7) * 8 + ((n >> 3) & 7);
  const int xq = n >> 6;
  const int b = bh >> 4, h = bh & 15;
  const int q = xq * (AT_WAVES * 32) + w * 32 + l31;

  const u16* Qp = Qh + (size_t)bh * S_N * DH_N;
  const u16* Kp = Kh + (size_t)bh * S_N * DH_N;
  const u16* Vp = Vt + (size_t)bh * DH_N * S_N;
  const uint32_t* mrow = mbits + ((size_t)b * S_N + q) * (S_N / 32);

  // Q as B-operand (col = l&31 = q, k-dim d = 16u + 8*hl + j), pre-scaled by C1
  short8 qf[4];
#pragma unroll
  for (int u = 0; u < 4; ++u)
    qf[u] = *reinterpret_cast<const short8*>(Qp + (size_t)q * DH_N + u * 16 + hl * 8);

  f32x16 oacc[2] = {};
  float m_run = -1e30f, l_run = 0.f;

  // stage one 64-key chunk: K[64][64] and V[64][64] (both 128B rows, 8 units),
  // global unit j = up ^ (row&7) lands in LDS unit slot up (linear dest).
  auto STAGE = [&](int buf, int kc) {
#pragma unroll
    for (int p = 0; p < 2; ++p) {
      const int s = p * 256 + t;
      const int row = s >> 3, up = s & 7, j = up ^ (row & 7);
      const u16* gk = Kp + (size_t)(kc * KVB + row) * DH_N + j * 8;
      const u16* gv = Vp + (size_t)row * S_N + kc * KVB + j * 8;
      u16* lk = &K_lds[buf][(p * 256 + w * 64) * 8];
      u16* lv = &V_lds[buf][(p * 256 + w * 64) * 8];
      __builtin_amdgcn_global_load_lds((gvoid_t*)gk, (lvoid_t*)lk, 16, 0, 0);
      __builtin_amdgcn_global_load_lds((gvoid_t*)gv, (lvoid_t*)lv, 16, 0, 0);
    }
  };

  // process one 32-key half of the staged chunk
  auto half = [&](int buf, int hh, uint32_t mw) {
    const int kb = hh * 32;
    short8 kf[4];
#pragma unroll
    for (int u = 0; u < 4; ++u)
      kf[u] = *reinterpret_cast<const short8*>(
          &K_lds[buf][(kb + l31) * DH_N + (((2 * u + hl) ^ kx) * 8)]);

    f32x16 z = {};
    __builtin_amdgcn_s_setprio(1);
    z = __builtin_amdgcn_mfma_f32_32x32x16_bf16(kf[0], qf[0], z, 0, 0, 0);
    z = __builtin_amdgcn_mfma_f32_32x32x16_bf16(kf[1], qf[1], z, 0, 0, 0);
    z = __builtin_amdgcn_mfma_f32_32x32x16_bf16(kf[2], qf[2], z, 0, 0, 0);
    z = __builtin_amdgcn_mfma_f32_32x32x16_bf16(kf[3], qf[3], z, 0, 0, 0);
    __builtin_amdgcn_s_setprio(0);

    short8 vf[2][2];
#pragma unroll
    for (int ks = 0; ks < 2; ++ks)
#pragma unroll
      for (int nf = 0; nf < 2; ++nf)
        vf[ks][nf] = *reinterpret_cast<const short8*>(
            &V_lds[buf][(nf * 32 + l31) * KVB + (((hh * 4 + ks * 2 + hl) ^ kx) * 8)]);

    if (mw) {
#pragma unroll
      for (int r = 0; r < 16; ++r)
        if ((mw >> ((r & 3) + 8 * (r >> 2) + 4 * hl)) & 1) z[r] = -1e30f;
    }

    // lane-local tree max; cross-half shuffle only on the rare rescale path
    float m8[8], m4[4];
#pragma unroll
    for (int r = 0; r < 8; ++r) m8[r] = fmaxf(z[2 * r], z[2 * r + 1]);
#pragma unroll
    for (int r = 0; r < 4; ++r) m4[r] = fmaxf(m8[2 * r], m8[2 * r + 1]);
    float mx = fmaxf(fmaxf(m4[0], m4[1]), fmaxf(m4[2], m4[3]));

    if (!__all(mx <= m_run + 8.0f)) {
      mx = fmaxf(mx, __shfl_xor(mx, 32));
      float mnew = fmaxf(m_run, mx);
      float al = __builtin_amdgcn_exp2f(m_run - mnew);
      l_run *= al;
#pragma unroll
      for (int r = 0; r < 16; ++r) { oacc[0][r] *= al; oacc[1][r] *= al; }
      m_run = mnew;
    }

    float p[16];
#pragma unroll
    for (int r = 0; r < 16; ++r) p[r] = __builtin_amdgcn_exp2f(z[r] - m_run);
    float a8[8], a4[4];
#pragma unroll
    for (int r = 0; r < 8; ++r) a8[r] = p[2 * r] + p[2 * r + 1];
#pragma unroll
    for (int r = 0; r < 4; ++r) a4[r] = a8[2 * r] + a8[2 * r + 1];
    l_run += (a4[0] + a4[1]) + (a4[2] + a4[3]);

    // lane-local P pack (V^T key-permuted so B-frag element j == p[j])
    union { uint32_t u[4]; short8 s8; } pf0, pf1;
    pf0.u[0] = pk_bf16(p[0], p[1]);   pf0.u[1] = pk_bf16(p[2], p[3]);
    pf0.u[2] = pk_bf16(p[4], p[5]);   pf0.u[3] = pk_bf16(p[6], p[7]);
    pf1.u[0] = pk_bf16(p[8], p[9]);   pf1.u[1] = pk_bf16(p[10], p[11]);
    pf1.u[2] = pk_bf16(p[12], p[13]); pf1.u[3] = pk_bf16(p[14], p[15]);

    __builtin_amdgcn_s_setprio(1);
    oacc[0] = __builtin_amdgcn_mfma_f32_32x32x16_bf16(vf[0][0], pf0.s8, oacc[0], 0, 0, 0);
    oacc[1] = __builtin_amdgcn_mfma_f32_32x32x16_bf16(vf[0][1], pf0.s8, oacc[1], 0, 0, 0);
    oacc[0] = __builtin_amdgcn_mfma_f32_32x32x16_bf16(vf[1][0], pf1.s8, oacc[0], 0, 0, 0);
    oacc[1] = __builtin_amdgcn_mfma_f32_32x32x16_bf16(vf[1][1], pf1.s8, oacc[1], 0, 0, 0);
    __builtin_amdgcn_s_setprio(0);
  };

  // ---- 2-phase pipeline: STAGE(next) || compute(cur); one barrier/chunk ----
  STAGE(0, 0);
  uint32_t mw0 = mrow[0], mw1 = mrow[1];
  __syncthreads();           // drains vmcnt(0): buf0 ready
  int cb = 0;
  for (int kc = 0; kc < NCH; ++kc) {
    uint32_t nmw0 = 0, nmw1 = 0;
    if (kc + 1 < NCH) {
      STAGE(cb ^ 1, kc + 1);
      nmw0 = mrow[2 * kc + 2];
      nmw1 = mrow[2 * kc + 3];
    }
    half(cb, 0, mw0);
    half(cb, 1, mw1);
    __syncthreads();         // drains stage of next buf; all waves done with cur
    cb ^= 1; mw0 = nmw0; mw1 = nmw1;
  }

  // --- finalize: one cross-half sum, then O^T[d][q]/l -> AO[b,q,h*64+d] ---
  float l_tot = l_run + __shfl_xor(l_run, 32);
  float inv_l = 1.0f / l_tot;
  u16* orow = AO + ((size_t)b * S_N + q) * DIM_N + h * DH_N;
#pragma unroll
  for (int nf = 0; nf < 2; ++nf)
#pragma unroll
    for (int g = 0; g < 4; ++g) {
      ushort4 v4;
      v4.x = f2bf(oacc[nf][g * 4 + 0] * inv_l);
      v4.y = f2bf(oacc[nf][g * 4 + 1] * inv_l);
      v4.z = f2bf(oacc[nf][g * 4 + 2] * inv_l);
      v4.w = f2bf(oacc[nf][g * 4 + 3] * inv_l);
      *reinterpret_cast<ushort4*>(orow + nf * 32 + g * 8 + hl * 4) = v4;
    }
}

// ---------------- launch ----------------
extern "C" void kernel_launch(void* const* d_in, const int* in_sizes, int n_in,
                              void* d_out, int out_size, void* d_ws, size_t ws_size,
                              hipStream_t stream)
{
  const float*   q_in = (const float*)d_in[0];
  const float*   k_in = (const float*)d_in[1];
  const float*   v_in = (const float*)d_in[2];
  const uint8_t* mask = (const uint8_t*)d_in[3];
  const float*   w_q  = (const float*)d_in[4];
  const float*   b_q  = (const float*)d_in[5];
  const float*   w_k  = (const float*)d_in[6];
  const float*   b_k  = (const float*)d_in[7];
  const float*   w_v  = (const float*)d_in[8];
  const float*   b_v  = (const float*)d_in[9];
  const float*   w_o  = (const float*)d_in[10];
  const float*   b_o  = (const float*)d_in[11];

  char* ws = (char*)d_ws;
  size_t off = 0;
  auto alloc = [&](size_t bytes) -> char* {
    char* p = ws + off;
    off += (bytes + 255) & ~(size_t)255;
    return p;
  };
  const size_t act_b = (size_t)M_ROWS * DIM_N * 2;
  const size_t w_b   = (size_t)DIM_N * DIM_N * 2;
  const int    nmw   = B_N * S_N * (S_N / 32);       // 524288 mask words
  u16* qb  = (u16*)alloc(act_b);
  u16* kb  = (u16*)alloc(act_b);
  u16* vb  = (u16*)alloc(act_b);
  u16* wqb = (u16*)alloc(w_b);
  u16* wkb = (u16*)alloc(w_b);
  u16* wvb = (u16*)alloc(w_b);
  u16* wob = (u16*)alloc(w_b);
  u16* Qh  = (u16*)alloc(act_b);
  u16* Kh  = (u16*)alloc(act_b);
  u16* Vt  = (u16*)alloc(act_b);
  uint32_t* mbits = (uint32_t*)alloc((size_t)nmw * 4);
  u16* AO  = qb;   // qb dead after Q projection; reuse for merged attn out

  const int n4a = M_ROWS * DIM_N / 4;
  const int n4w = DIM_N * DIM_N / 4;
  cvt_kernel<<<n4a / 256, 256, 0, stream>>>(q_in, qb, n4a);
  cvt_kernel<<<n4a / 256, 256, 0, stream>>>(k_in, kb, n4a);
  cvt_kernel<<<n4a / 256, 256, 0, stream>>>(v_in, vb, n4a);
  cvt_kernel<<<n4w / 256, 256, 0, stream>>>(w_q, wqb, n4w);
  cvt_kernel<<<n4w / 256, 256, 0, stream>>>(w_k, wkb, n4w);
  cvt_kernel<<<n4w / 256, 256, 0, stream>>>(w_v, wvb, n4w);
  cvt_kernel<<<n4w / 256, 256, 0, stream>>>(w_o, wob, n4w);
  pack_mask<<<nmw / 256, 256, 0, stream>>>(mask, mbits, nmw);

  dim3 gg(M_ROWS / 128, DIM_N / 128);
  gemm_bt<0><<<gg, 256, 0, stream>>>(qb, wqb, b_q, Qh, C1);
  gemm_bt<0><<<gg, 256, 0, stream>>>(kb, wkb, b_k, Kh, 1.0f);
  gemm_bt<1><<<gg, 256, 0, stream>>>(vb, wvb, b_v, Vt, 1.0f);

  attn_kernel<<<dim3(S_N / (AT_WAVES * 32), BH_N), 256, 0, stream>>>(Qh, Kh, Vt, mbits, AO);

  gemm_bt<2><<<gg, 256, 0, stream>>>(AO, wob, b_o, (float*)d_out, 1.0f);
}

// Round 8
// 258.711 us; speedup vs baseline: 1.6250x; 1.1091x over previous
//
#include <hip/hip_runtime.h>
#include <hip/hip_bf16.h>
#include <stdint.h>

#define B_N 4
#define S_N 2048
#define DIM_N 1024
#define H_N 16
#define DH_N 64
#define M_ROWS (B_N * S_N)   /* 8192 */
#define BH_N (B_N * H_N)     /* 64 */
#define C1 0.18033688011112042f   /* 0.125 * log2(e) */

typedef unsigned short u16;
typedef __attribute__((ext_vector_type(8))) short short8;
typedef __attribute__((ext_vector_type(4))) float f32x4;
typedef __attribute__((ext_vector_type(16))) float f32x16;

typedef __attribute__((address_space(1))) const void gvoid_t;
typedef __attribute__((address_space(3))) void lvoid_t;

__device__ __forceinline__ u16 f2bf(float f) {
  union { float f; uint32_t u; } c; c.f = f;
  uint32_t u = c.u;
  return (u16)((u + 0x7FFFu + ((u >> 16) & 1u)) >> 16);
}

// compiler-visible packed f32x2 -> bf16x2 (lowers to v_cvt_pk_bf16_f32;
// hazards handled by the backend — NO inline asm, per T12/m240 guidance)
__device__ __forceinline__ uint32_t pk2(float lo, float hi) {
  float2 f; f.x = lo; f.y = hi;
  __hip_bfloat162 h = __float22bfloat162_rn(f);
  union { __hip_bfloat162 h; uint32_t u; } c; c.h = h;
  return c.u;
}

// ---------------- fp32 -> bf16 conversion (vectorized) ----------------
__global__ void cvt_kernel(const float* __restrict__ src, u16* __restrict__ dst, int n4) {
  int i = blockIdx.x * blockDim.x + threadIdx.x;
  if (i >= n4) return;
  float4 v = reinterpret_cast<const float4*>(src)[i];
  ushort4 o;
  o.x = f2bf(v.x); o.y = f2bf(v.y); o.z = f2bf(v.z); o.w = f2bf(v.w);
  reinterpret_cast<ushort4*>(dst)[i] = o;
}

// ---------------- mask -> packed bits (1 bit per bool, 32 keys/word) ------
__global__ void pack_mask(const uint8_t* __restrict__ m, uint32_t* __restrict__ bits, int nwords) {
  int i = blockIdx.x * blockDim.x + threadIdx.x;
  if (i >= nwords) return;
  const uint32_t* p = reinterpret_cast<const uint32_t*>(m) + (size_t)i * 8;
  uint32_t out = 0;
#pragma unroll
  for (int w = 0; w < 8; ++w) {
    uint32_t v = p[w];
    if (v & 0x000000FFu) out |= 1u << (w * 4 + 0);
    if (v & 0x0000FF00u) out |= 1u << (w * 4 + 1);
    if (v & 0x00FF0000u) out |= 1u << (w * 4 + 2);
    if (v & 0xFF000000u) out |= 1u << (w * 4 + 3);
  }
  bits[i] = out;
}

// ---------------- bf16 GEMM, C[m][n] = (sum_k A[m][k]*Bw[n][k] + bias[n])*scale
// MODE 0: bf16 out, permuted [b,h,s,d]   (Q with scale=C1, K with scale=1)
// MODE 1: bf16 out, transposed [b,h,d,s'] with within-16 key permutation
//         s' = s^12 for (s&15) in [4,12)  -- pairs with attn's lane-local P pack
// MODE 2: fp32 out, row-major [m][n]     (final output projection)
template<int MODE>
__global__ __launch_bounds__(256)
void gemm_bt(const u16* __restrict__ A, const u16* __restrict__ Bw,
             const float* __restrict__ bias, void* __restrict__ outp, float scale)
{
  __shared__ __align__(16) u16 As[128 * 32];
  __shared__ __align__(16) u16 Bs[128 * 32];
  const int m0 = blockIdx.x * 128, n0 = blockIdx.y * 128;
  const int t = threadIdx.x, w = t >> 6;
  const int l = t & 63, lr = l & 15, lg = l >> 4;
  const int wr = (w >> 1) * 64, wc = (w & 1) * 64;
  const int srow = t >> 2;
  const int skoff = (t & 3) * 8;

  f32x4 acc[4][4] = {};

  for (int k0 = 0; k0 < DIM_N; k0 += 32) {
    __syncthreads();
#pragma unroll
    for (int c = 0; c < 2; ++c) {
      const u16* ga = A  + (size_t)(m0 + c * 64 + srow) * DIM_N + k0 + skoff;
      const u16* gb = Bw + (size_t)(n0 + c * 64 + srow) * DIM_N + k0 + skoff;
      u16* la = &As[(c * 64 + 16 * w) * 32];
      u16* lb = &Bs[(c * 64 + 16 * w) * 32];
      __builtin_amdgcn_global_load_lds((gvoid_t*)ga, (lvoid_t*)la, 16, 0, 0);
      __builtin_amdgcn_global_load_lds((gvoid_t*)gb, (lvoid_t*)lb, 16, 0, 0);
    }
    __syncthreads();

    short8 af[4], bfr[4];
#pragma unroll
    for (int mf = 0; mf < 4; ++mf)
      af[mf] = *reinterpret_cast<const short8*>(&As[(wr + mf * 16 + lr) * 32 + lg * 8]);
#pragma unroll
    for (int nf = 0; nf < 4; ++nf)
      bfr[nf] = *reinterpret_cast<const short8*>(&Bs[(wc + nf * 16 + lr) * 32 + lg * 8]);
#pragma unroll
    for (int mf = 0; mf < 4; ++mf)
#pragma unroll
      for (int nf = 0; nf < 4; ++nf)
        acc[mf][nf] = __builtin_amdgcn_mfma_f32_16x16x32_bf16(af[mf], bfr[nf], acc[mf][nf], 0, 0, 0);
  }

  float bv[4];
#pragma unroll
  for (int nf = 0; nf < 4; ++nf) bv[nf] = bias[n0 + wc + nf * 16 + lr];

#pragma unroll
  for (int mf = 0; mf < 4; ++mf)
#pragma unroll
    for (int nf = 0; nf < 4; ++nf)
#pragma unroll
      for (int r = 0; r < 4; ++r) {
        int grow = m0 + wr + mf * 16 + lg * 4 + r;
        int gcol = n0 + wc + nf * 16 + lr;
        float v = (acc[mf][nf][r] + bv[nf]) * scale;
        if (MODE == 2) {
          ((float*)outp)[(size_t)grow * DIM_N + gcol] = v;
        } else {
          int b = grow >> 11, s = grow & 2047;
          int h = gcol >> 6, d = gcol & 63;
          size_t idx;
          if (MODE == 0) {
            idx = ((size_t)(b * H_N + h) * S_N + s) * DH_N + d;
          } else {
            int sp = ((((s & 15) + 4) & 8) ? (s ^ 12) : s);  // within-16 key perm
            idx = ((size_t)(b * H_N + h) * DH_N + d) * S_N + sp;
          }
          ((u16*)outp)[idx] = f2bf(v);
        }
      }
}

// ---------------- flash attention: LDS-staged KV, 64 q-rows per wave -------
// grid (64, 8): bh = (bx&7)*8 + (bx>>3) so bh>>3 = bx&7 = linear%8 -> all 8
// q-blocks of a bh land on one XCD (per-XCD KV = 8 bh x 512KB = 4MB = its L2).
// Each wave owns TWO 32-col q-groups sharing one K/V fragment read -> LDS
// read + DMA traffic halves vs 32q/wave; the groups' softmax/PV chains are
// independent (2x intra-wave ILP). K,V double-buffered in LDS via
// global_load_lds (pre-swizzled source unit j = up ^ (row&7); reads XOR back).
#define AT_WAVES 4
#define QPW 64
#define KVB 64
#define NCH (S_N / KVB)   /* 32 */

__global__ __launch_bounds__(256, 2)
void attn_kernel(const u16* __restrict__ Qh, const u16* __restrict__ Kh,
                 const u16* __restrict__ Vt, const uint32_t* __restrict__ mbits,
                 u16* __restrict__ AO)
{
  __shared__ __align__(16) u16 K_lds[2][KVB * DH_N];   // 8KB per buf
  __shared__ __align__(16) u16 V_lds[2][DH_N * KVB];   // 8KB per buf

  const int t = threadIdx.x;
  const int w = t >> 6, l = t & 63;
  const int l31 = l & 31, hl = l >> 5;
  const int kx = l31 & 7;

  const int bx = blockIdx.x;
  const int bh = (bx & 7) * 8 + (bx >> 3);   // bh>>3 == bx&7 == XCD
  const int b = bh >> 4, h = bh & 15;
  const int q0 = blockIdx.y * (AT_WAVES * QPW) + w * QPW;

  const u16* Qp = Qh + (size_t)bh * S_N * DH_N;
  const u16* Kp = Kh + (size_t)bh * S_N * DH_N;
  const u16* Vp = Vt + (size_t)bh * DH_N * S_N;
  const uint32_t* mrow0 = mbits + ((size_t)b * S_N + q0 + l31) * (S_N / 32);
  const uint32_t* mrow1 = mbits + ((size_t)b * S_N + q0 + 32 + l31) * (S_N / 32);

  // Q as B-operand, two 32-col groups (col = l&31, k-dim d = 16u+8hl+j), *C1
  short8 qf0[4], qf1[4];
#pragma unroll
  for (int u = 0; u < 4; ++u) {
    qf0[u] = *reinterpret_cast<const short8*>(
        Qp + (size_t)(q0 + l31) * DH_N + u * 16 + hl * 8);
    qf1[u] = *reinterpret_cast<const short8*>(
        Qp + (size_t)(q0 + 32 + l31) * DH_N + u * 16 + hl * 8);
  }

  f32x16 o00 = {}, o01 = {}, o10 = {}, o11 = {};
  float mr0 = -1e30f, mr1 = -1e30f, lr0 = 0.f, lr1 = 0.f;

  // stage one 64-key chunk: K[64][64], V^T[64 d][64 keys] (128B rows, 8 units)
  // global unit j = up ^ (row&7) lands linearly in LDS slot (row, up).
  auto STAGE = [&](int buf, int kc) {
#pragma unroll
    for (int p = 0; p < 2; ++p) {
      const int s = p * 256 + t;
      const int row = s >> 3, up = s & 7, j = up ^ (row & 7);
      const u16* gk = Kp + (size_t)(kc * KVB + row) * DH_N + j * 8;
      const u16* gv = Vp + (size_t)row * S_N + kc * KVB + j * 8;
      u16* lk = &K_lds[buf][(p * 256 + w * 64) * 8];
      u16* lv = &V_lds[buf][(p * 256 + w * 64) * 8];
      __builtin_amdgcn_global_load_lds((gvoid_t*)gk, (lvoid_t*)lk, 16, 0, 0);
      __builtin_amdgcn_global_load_lds((gvoid_t*)gv, (lvoid_t*)lv, 16, 0, 0);
    }
  };

  // softmax + PV for one q-group (named by-ref state; no runtime indexing)
  auto softpv = [&](f32x16& z, uint32_t mw, float& mr, float& lr,
                    f32x16& oA, f32x16& oB, const short8 vf[2][2]) {
    if (mw) {
#pragma unroll
      for (int r = 0; r < 16; ++r)
        if ((mw >> ((r & 3) + 8 * (r >> 2) + 4 * hl)) & 1) z[r] = -1e30f;
    }

    float m8[8], m4[4];
#pragma unroll
    for (int r = 0; r < 8; ++r) m8[r] = fmaxf(z[2 * r], z[2 * r + 1]);
#pragma unroll
    for (int r = 0; r < 4; ++r) m4[r] = fmaxf(m8[2 * r], m8[2 * r + 1]);
    float mx = fmaxf(fmaxf(m4[0], m4[1]), fmaxf(m4[2], m4[3]));

    if (!__all(mx <= mr + 8.0f)) {
      mx = fmaxf(mx, __shfl_xor(mx, 32));
      float mnew = fmaxf(mr, mx);
      float al = __builtin_amdgcn_exp2f(mr - mnew);
      lr *= al;
#pragma unroll
      for (int r = 0; r < 16; ++r) { oA[r] *= al; oB[r] *= al; }
      mr = mnew;
    }

    float p[16];
#pragma unroll
    for (int r = 0; r < 16; ++r) p[r] = __builtin_amdgcn_exp2f(z[r] - mr);
    float a8[8], a4[4];
#pragma unroll
    for (int r = 0; r < 8; ++r) a8[r] = p[2 * r] + p[2 * r + 1];
#pragma unroll
    for (int r = 0; r < 4; ++r) a4[r] = a8[2 * r] + a8[2 * r + 1];
    lr += (a4[0] + a4[1]) + (a4[2] + a4[3]);

    // lane-local P pack (V^T key-permuted so B-frag element j == p[j])
    union { uint32_t u[4]; short8 s8; } pf0, pf1;
    pf0.u[0] = pk2(p[0], p[1]);   pf0.u[1] = pk2(p[2], p[3]);
    pf0.u[2] = pk2(p[4], p[5]);   pf0.u[3] = pk2(p[6], p[7]);
    pf1.u[0] = pk2(p[8], p[9]);   pf1.u[1] = pk2(p[10], p[11]);
    pf1.u[2] = pk2(p[12], p[13]); pf1.u[3] = pk2(p[14], p[15]);

    __builtin_amdgcn_s_setprio(1);
    oA = __builtin_amdgcn_mfma_f32_32x32x16_bf16(vf[0][0], pf0.s8, oA, 0, 0, 0);
    oB = __builtin_amdgcn_mfma_f32_32x32x16_bf16(vf[0][1], pf0.s8, oB, 0, 0, 0);
    oA = __builtin_amdgcn_mfma_f32_32x32x16_bf16(vf[1][0], pf1.s8, oA, 0, 0, 0);
    oB = __builtin_amdgcn_mfma_f32_32x32x16_bf16(vf[1][1], pf1.s8, oB, 0, 0, 0);
    __builtin_amdgcn_s_setprio(0);
  };

  // process one 32-key half of the staged chunk for both q-groups
  auto half = [&](int buf, int hh, uint32_t mwg0, uint32_t mwg1) {
    const int kb = hh * 32;
    short8 kf[4];
#pragma unroll
    for (int u = 0; u < 4; ++u)
      kf[u] = *reinterpret_cast<const short8*>(
          &K_lds[buf][(kb + l31) * DH_N + (((2 * u + hl) ^ kx) * 8)]);

    f32x16 z0 = {}, z1 = {};
    __builtin_amdgcn_s_setprio(1);
    z0 = __builtin_amdgcn_mfma_f32_32x32x16_bf16(kf[0], qf0[0], z0, 0, 0, 0);
    z1 = __builtin_amdgcn_mfma_f32_32x32x16_bf16(kf[0], qf1[0], z1, 0, 0, 0);
    z0 = __builtin_amdgcn_mfma_f32_32x32x16_bf16(kf[1], qf0[1], z0, 0, 0, 0);
    z1 = __builtin_amdgcn_mfma_f32_32x32x16_bf16(kf[1], qf1[1], z1, 0, 0, 0);
    z0 = __builtin_amdgcn_mfma_f32_32x32x16_bf16(kf[2], qf0[2], z0, 0, 0, 0);
    z1 = __builtin_amdgcn_mfma_f32_32x32x16_bf16(kf[2], qf1[2], z1, 0, 0, 0);
    z0 = __builtin_amdgcn_mfma_f32_32x32x16_bf16(kf[3], qf0[3], z0, 0, 0, 0);
    z1 = __builtin_amdgcn_mfma_f32_32x32x16_bf16(kf[3], qf1[3], z1, 0, 0, 0);
    __builtin_amdgcn_s_setprio(0);

    short8 vf[2][2];
#pragma unroll
    for (int ks = 0; ks < 2; ++ks)
#pragma unroll
      for (int nf = 0; nf < 2; ++nf)
        vf[ks][nf] = *reinterpret_cast<const short8*>(
            &V_lds[buf][(nf * 32 + l31) * KVB + (((hh * 4 + ks * 2 + hl) ^ kx) * 8)]);

    softpv(z0, mwg0, mr0, lr0, o00, o01, vf);
    softpv(z1, mwg1, mr1, lr1, o10, o11, vf);
  };

  // ---- 2-phase pipeline: STAGE(next) || compute(cur); one barrier/chunk ----
  STAGE(0, 0);
  __syncthreads();           // buf0 ready
  int cb = 0;
  for (int kc = 0; kc < NCH; ++kc) {
    uint32_t mw00 = mrow0[2 * kc],     mw10 = mrow1[2 * kc];
    uint32_t mw01 = mrow0[2 * kc + 1], mw11 = mrow1[2 * kc + 1];
    if (kc + 1 < NCH) STAGE(cb ^ 1, kc + 1);
    half(cb, 0, mw00, mw10);
    half(cb, 1, mw01, mw11);
    __syncthreads();         // next buf staged; all waves done with cur
    cb ^= 1;
  }

  // --- finalize: one cross-half sum per group, O^T/l -> AO[b,q,h*64+d] ---
  auto fin = [&](float lr, int qg, const f32x16& oA, const f32x16& oB) {
    float l_tot = lr + __shfl_xor(lr, 32);
    float inv_l = 1.0f / l_tot;
    u16* orow = AO + ((size_t)b * S_N + q0 + qg + l31) * DIM_N + h * DH_N;
#pragma unroll
    for (int gg = 0; gg < 4; ++gg) {
      ushort4 v4;
      v4.x = f2bf(oA[gg * 4 + 0] * inv_l);
      v4.y = f2bf(oA[gg * 4 + 1] * inv_l);
      v4.z = f2bf(oA[gg * 4 + 2] * inv_l);
      v4.w = f2bf(oA[gg * 4 + 3] * inv_l);
      *reinterpret_cast<ushort4*>(orow + gg * 8 + hl * 4) = v4;
      ushort4 w4;
      w4.x = f2bf(oB[gg * 4 + 0] * inv_l);
      w4.y = f2bf(oB[gg * 4 + 1] * inv_l);
      w4.z = f2bf(oB[gg * 4 + 2] * inv_l);
      w4.w = f2bf(oB[gg * 4 + 3] * inv_l);
      *reinterpret_cast<ushort4*>(orow + 32 + gg * 8 + hl * 4) = w4;
    }
  };
  fin(lr0, 0, o00, o01);
  fin(lr1, 32, o10, o11);
}

// ---------------- launch ----------------
extern "C" void kernel_launch(void* const* d_in, const int* in_sizes, int n_in,
                              void* d_out, int out_size, void* d_ws, size_t ws_size,
                              hipStream_t stream)
{
  const float*   q_in = (const float*)d_in[0];
  const float*   k_in = (const float*)d_in[1];
  const float*   v_in = (const float*)d_in[2];
  const uint8_t* mask = (const uint8_t*)d_in[3];
  const float*   w_q  = (const float*)d_in[4];
  const float*   b_q  = (const float*)d_in[5];
  const float*   w_k  = (const float*)d_in[6];
  const float*   b_k  = (const float*)d_in[7];
  const float*   w_v  = (const float*)d_in[8];
  const float*   b_v  = (const float*)d_in[9];
  const float*   w_o  = (const float*)d_in[10];
  const float*   b_o  = (const float*)d_in[11];

  char* ws = (char*)d_ws;
  size_t off = 0;
  auto alloc = [&](size_t bytes) -> char* {
    char* p = ws + off;
    off += (bytes + 255) & ~(size_t)255;
    return p;
  };
  const size_t act_b = (size_t)M_ROWS * DIM_N * 2;
  const size_t w_b   = (size_t)DIM_N * DIM_N * 2;
  const int    nmw   = B_N * S_N * (S_N / 32);       // 524288 mask words
  u16* qb  = (u16*)alloc(act_b);
  u16* kb  = (u16*)alloc(act_b);
  u16* vb  = (u16*)alloc(act_b);
  u16* wqb = (u16*)alloc(w_b);
  u16* wkb = (u16*)alloc(w_b);
  u16* wvb = (u16*)alloc(w_b);
  u16* wob = (u16*)alloc(w_b);
  u16* Qh  = (u16*)alloc(act_b);
  u16* Kh  = (u16*)alloc(act_b);
  u16* Vt  = (u16*)alloc(act_b);
  uint32_t* mbits = (uint32_t*)alloc((size_t)nmw * 4);
  u16* AO  = qb;   // qb dead after Q projection; reuse for merged attn out

  const int n4a = M_ROWS * DIM_N / 4;
  const int n4w = DIM_N * DIM_N / 4;
  cvt_kernel<<<n4a / 256, 256, 0, stream>>>(q_in, qb, n4a);
  cvt_kernel<<<n4a / 256, 256, 0, stream>>>(k_in, kb, n4a);
  cvt_kernel<<<n4a / 256, 256, 0, stream>>>(v_in, vb, n4a);
  cvt_kernel<<<n4w / 256, 256, 0, stream>>>(w_q, wqb, n4w);
  cvt_kernel<<<n4w / 256, 256, 0, stream>>>(w_k, wkb, n4w);
  cvt_kernel<<<n4w / 256, 256, 0, stream>>>(w_v, wvb, n4w);
  cvt_kernel<<<n4w / 256, 256, 0, stream>>>(w_o, wob, n4w);
  pack_mask<<<nmw / 256, 256, 0, stream>>>(mask, mbits, nmw);

  dim3 gg(M_ROWS / 128, DIM_N / 128);
  gemm_bt<0><<<gg, 256, 0, stream>>>(qb, wqb, b_q, Qh, C1);
  gemm_bt<0><<<gg, 256, 0, stream>>>(kb, wkb, b_k, Kh, 1.0f);
  gemm_bt<1><<<gg, 256, 0, stream>>>(vb, wvb, b_v, Vt, 1.0f);

  attn_kernel<<<dim3(64, S_N / (AT_WAVES * QPW)), 256, 0, stream>>>(Qh, Kh, Vt, mbits, AO);

  gemm_bt<2><<<gg, 256, 0, stream>>>(AO, wob, b_o, (float*)d_out, 1.0f);
}